// Round 13
// baseline (140.130 us; speedup 1.0000x reference)
//
#include <hip/hip_runtime.h>
#include <stdint.h>
#include <stddef.h>

typedef int v4i __attribute__((ext_vector_type(4)));

#define GLOAD_LDS16(g, l) __builtin_amdgcn_global_load_lds( \
    (const __attribute__((address_space(1))) void*)(g),     \
    (__attribute__((address_space(3))) void*)(l), 16, 0, 0)

// ---------------------------------------------------------------------------
// Quantize x rows (length 2048): one wave per row, 4 rows per block.
// scale = max(amax/127, floorv); q = clip(rint(v/scale), -128, 127)
// ---------------------------------------------------------------------------
__device__ __forceinline__ int pack4(float4 f, float s) {
    int a = (int)rintf(f.x / s); a = a < -128 ? -128 : (a > 127 ? 127 : a);
    int b = (int)rintf(f.y / s); b = b < -128 ? -128 : (b > 127 ? 127 : b);
    int c = (int)rintf(f.z / s); c = c < -128 ? -128 : (c > 127 ? 127 : c);
    int d = (int)rintf(f.w / s); d = d < -128 ? -128 : (d > 127 ? 127 : d);
    return (a & 255) | ((b & 255) << 8) | ((c & 255) << 16) | ((d & 255) << 24);
}

__global__ __launch_bounds__(256) void quant_rows_2048(
    const float* __restrict__ in, signed char* __restrict__ q,
    float* __restrict__ scales, float floorv)
{
    const int lane = threadIdx.x & 63;
    const int row  = blockIdx.x * 4 + (threadIdx.x >> 6);
    const float* rp = in + (size_t)row * 2048;

    float4 v[8];
#pragma unroll
    for (int j = 0; j < 2; ++j) {
        const float4* p = (const float4*)(rp + j * 1024 + lane * 16);
#pragma unroll
        for (int i = 0; i < 4; ++i) v[j * 4 + i] = p[i];
    }
    float am = 0.0f;
#pragma unroll
    for (int i = 0; i < 8; ++i) {
        am = fmaxf(am, fabsf(v[i].x));
        am = fmaxf(am, fabsf(v[i].y));
        am = fmaxf(am, fabsf(v[i].z));
        am = fmaxf(am, fabsf(v[i].w));
    }
#pragma unroll
    for (int off = 32; off; off >>= 1) am = fmaxf(am, __shfl_xor(am, off));
    const float s = fmaxf(am / 127.0f, floorv);

#pragma unroll
    for (int j = 0; j < 2; ++j) {
        int4 pk;
        pk.x = pack4(v[j * 4 + 0], s);
        pk.y = pack4(v[j * 4 + 1], s);
        pk.z = pack4(v[j * 4 + 2], s);
        pk.w = pack4(v[j * 4 + 3], s);
        *(int4*)(q + (size_t)row * 2048 + j * 1024 + lane * 16) = pk;
    }
    if (lane == 0) scales[row] = s;
}

// ---------------------------------------------------------------------------
// Quantize w rows AND store MFMA-fragment-native: 1KB blocks (f=col/16, t64):
// block byte l*16.. = wq[f*16 + (l&15)][t64*64 + (l>>4)*16 .. +16]  — one
// coalesced global_load_dwordx4 per wave = one B fragment. (Verified R11/12.)
// ---------------------------------------------------------------------------
__global__ __launch_bounds__(256) void quant_w_t(
    const float* __restrict__ in, signed char* __restrict__ qt,
    float* __restrict__ scales)
{
    const int lane = threadIdx.x & 63;
    const int row  = blockIdx.x * 4 + (threadIdx.x >> 6);
    const int f    = row >> 4;
    const int rl   = row & 15;
    const float* rp = in + (size_t)row * 2048;

    float4 v[8];
#pragma unroll
    for (int j = 0; j < 2; ++j) {
        const float4* p = (const float4*)(rp + j * 1024 + lane * 16);
#pragma unroll
        for (int i = 0; i < 4; ++i) v[j * 4 + i] = p[i];
    }
    float am = 0.0f;
#pragma unroll
    for (int i = 0; i < 8; ++i) {
        am = fmaxf(am, fabsf(v[i].x));
        am = fmaxf(am, fabsf(v[i].y));
        am = fmaxf(am, fabsf(v[i].z));
        am = fmaxf(am, fabsf(v[i].w));
    }
#pragma unroll
    for (int off = 32; off; off >>= 1) am = fmaxf(am, __shfl_xor(am, off));
    const float s = fmaxf(am / 127.0f, 1e-8f / 127.0f);

#pragma unroll
    for (int j = 0; j < 2; ++j) {
        int4 pk;
        pk.x = pack4(v[j * 4 + 0], s);
        pk.y = pack4(v[j * 4 + 1], s);
        pk.z = pack4(v[j * 4 + 2], s);
        pk.w = pack4(v[j * 4 + 3], s);
        const int kb  = j * 64 + lane;      // 16B-chunk index 0..127
        const int t   = kb >> 2;            // t64 0..31
        const int sub = kb & 3;             // k-quarter within 64
        *(int4*)(qt + (((size_t)(f * 32 + t)) << 10) + (rl << 4) + (sub << 8)) = pk;
    }
    if (lane == 0) scales[row] = s;
}

// ---------------------------------------------------------------------------
// int8 GEMM — m201 geometry for i8: 64 MFMA per wave per sync window.
// 256x256 block, BK=128, 512 thr = 8 waves (2M x 4N), wave-tile 128x64 via
// 8m x 4n frags x 2 k-slices of mfma_i32_16x16x64_i8 = 64 MFMA/wave/K-tile
// (acc[8][4] = 128 VGPR; 2 waves/SIMD; 1 block/CU — m201's occupancy).
// A: LDS ring-3 x 32KB = 96KB, staged 4x gload_lds/thread/tile (1 per phase).
// B: frag-native from wq_t — 8 coalesced 1KB loads/tile at P0 (compiler vmcnt).
// 4 phases/tile: {4 ds_read quadrant | 1 ST_A | BAR | lgkm0+schb | prio1
//   16 MFMA prio0 | BAR}; counted vmcnt(4) ONCE per tile (drains ST_A(t+1),
//   never 0 mid-loop; tail 4->0). Per-window MFMA per SIMD: 2x64x20.4 =
//   2611 cyc vs LDS ~1550 — MFMA-dominant for the first time.
// Swizzle: LDS chunk c of row r holds global chunk c^(r&7); read chunk
//   (q ^ (rl&7)) — even bank spread, ~2-way = free (R12: 0 conflicts).
// ---------------------------------------------------------------------------
__global__ __launch_bounds__(512, 2) void gemm_i8_m201(
    const signed char* __restrict__ xq, const signed char* __restrict__ wqt,
    const float* __restrict__ xs, const float* __restrict__ ws,
    const float* __restrict__ bias, float* __restrict__ out, int K)
{
    __shared__ __align__(16) signed char lds[98304]; // 3 x A[32768]

    const int tid  = threadIdx.x;
    const int lane = tid & 63;
    const int wid  = tid >> 6;        // 0..7
    const int wm   = wid >> 2;        // 0..1
    const int wn   = wid & 3;         // 0..3

    const int nwg  = gridDim.x * gridDim.y;
    int orig = blockIdx.y * gridDim.x + blockIdx.x;
    int swz  = ((nwg & 7) == 0) ? ((orig & 7) * (nwg >> 3) + (orig >> 3)) : orig;
    const int brow = (swz / gridDim.x) * 256;
    const int bcol = (swz % gridDim.x) * 256;

    // A staging: thread -> (row = 64s + (tid>>3), chunk = tid&7), swz source
    const int gch = (((tid & 7) ^ ((tid >> 3) & 7)) << 4);
    const signed char* gA = xq + (size_t)(brow + (tid >> 3)) * K;

#define ST_A(tt, bb, s) GLOAD_LDS16(                                          \
    gA + (size_t)(64 * (s)) * K + (size_t)(tt) * 128 + gch,                   \
    lds + (bb) * 32768 + (s) * 8192 + (tid << 4))

    const int rl = lane & 15;
    const int ko = lane >> 4;

#define FRAG_A(bb, r, q) (*(const v4i*)(lds + (bb) * 32768 + (r) * 128 + \
                                        ((((q) ^ ((r) & 7))) << 4)))

    // B frag-native: wave covers frags f0..f0+3, k-slots 2t,2t+1
    const int NT64 = K >> 6;   // 32
    const signed char* gB = wqt + (((size_t)((bcol >> 4) + wn * 4) * NT64) << 10) + (lane << 4);
    const size_t bns = ((size_t)NT64) << 10;

    v4i acc[8][4] = {};
    const int ar = wm * 128 + rl;

#define MFMA16(MB, KS)                                                                     \
    do {                                                                                   \
        __builtin_amdgcn_s_setprio(1);                                                     \
        _Pragma("unroll")                                                                  \
        for (int mm = 0; mm < 4; ++mm) {                                                   \
            acc[MB + mm][0] = __builtin_amdgcn_mfma_i32_16x16x64_i8(af[mm], bc[KS*4+0], acc[MB + mm][0], 0, 0, 0); \
            acc[MB + mm][1] = __builtin_amdgcn_mfma_i32_16x16x64_i8(af[mm], bc[KS*4+1], acc[MB + mm][1], 0, 0, 0); \
            acc[MB + mm][2] = __builtin_amdgcn_mfma_i32_16x16x64_i8(af[mm], bc[KS*4+2], acc[MB + mm][2], 0, 0, 0); \
            acc[MB + mm][3] = __builtin_amdgcn_mfma_i32_16x16x64_i8(af[mm], bc[KS*4+3], acc[MB + mm][3], 0, 0, 0); \
        }                                                                                  \
        __builtin_amdgcn_s_setprio(0);                                                     \
    } while (0)

#define BAR()  __builtin_amdgcn_s_barrier()
#define LGKM0() do { asm volatile("s_waitcnt lgkmcnt(0)" ::: "memory"); \
                     __builtin_amdgcn_sched_barrier(0); } while (0)

    // ---- prologue: stage A(0)->buf0, A(1)->buf1; tile-0 resident; barrier
    ST_A(0, 0, 0); ST_A(0, 0, 1); ST_A(0, 0, 2); ST_A(0, 0, 3);
    ST_A(1, 1, 0); ST_A(1, 1, 1); ST_A(1, 1, 2); ST_A(1, 1, 3);
    asm volatile("s_waitcnt vmcnt(4)" ::: "memory");
    BAR();

    const int NT = K >> 7;   // 16
    for (int t = 0; t < NT; ++t) {
        const int buf = t % 3;
        const int nb  = (t + 2) % 3;
        const bool st = (t + 2 < NT);
        v4i af[4], bc[8];

        // ---- P0: A m0..3 ks0; all 8 B loads; ST s0
        af[0] = FRAG_A(buf, ar,      ko);
        af[1] = FRAG_A(buf, ar + 16, ko);
        af[2] = FRAG_A(buf, ar + 32, ko);
        af[3] = FRAG_A(buf, ar + 48, ko);
        {
            const signed char* gBt = gB + (((size_t)(2 * t)) << 10);
#pragma unroll
            for (int n = 0; n < 4; ++n) {
                bc[n]     = *(const v4i*)(gBt + n * bns);
                bc[4 + n] = *(const v4i*)(gBt + n * bns + 1024);
            }
        }
        if (st) ST_A(t + 2, nb, 0);
        BAR(); LGKM0();
        MFMA16(0, 0);
        BAR();

        // ---- P1: A m4..7 ks0; ST s1
        af[0] = FRAG_A(buf, ar + 64,  ko);
        af[1] = FRAG_A(buf, ar + 80,  ko);
        af[2] = FRAG_A(buf, ar + 96,  ko);
        af[3] = FRAG_A(buf, ar + 112, ko);
        if (st) ST_A(t + 2, nb, 1);
        BAR(); LGKM0();
        MFMA16(4, 0);
        BAR();

        // ---- P2: A m0..3 ks1; ST s2
        af[0] = FRAG_A(buf, ar,      4 + ko);
        af[1] = FRAG_A(buf, ar + 16, 4 + ko);
        af[2] = FRAG_A(buf, ar + 32, 4 + ko);
        af[3] = FRAG_A(buf, ar + 48, 4 + ko);
        if (st) ST_A(t + 2, nb, 2);
        BAR(); LGKM0();
        MFMA16(0, 1);
        BAR();

        // ---- P3: A m4..7 ks1; ST s3; tile-end counted vmcnt + barrier
        af[0] = FRAG_A(buf, ar + 64,  4 + ko);
        af[1] = FRAG_A(buf, ar + 80,  4 + ko);
        af[2] = FRAG_A(buf, ar + 96,  4 + ko);
        af[3] = FRAG_A(buf, ar + 112, 4 + ko);
        if (st) ST_A(t + 2, nb, 3);
        BAR(); LGKM0();
        MFMA16(4, 1);

        if (t + 2 < NT) {
            asm volatile("s_waitcnt vmcnt(4)" ::: "memory");  // ST_A(t+1) drained
            BAR();
        } else if (t + 2 == NT) {
            asm volatile("s_waitcnt vmcnt(0)" ::: "memory");  // drain ST_A(NT-1)
            BAR();
        }
        // t == NT-1: fall through to epilogue
    }

    // ---- epilogue: C/D layout col = lane&15, row = (lane>>4)*4 + j
    const int rg = lane >> 4;
#pragma unroll
    for (int n = 0; n < 4; ++n) {
        const int col = bcol + wn * 64 + n * 16 + rl;
        const float wsc = ws[col];
        const float bv  = bias[col];
#pragma unroll
        for (int m = 0; m < 8; ++m) {
#pragma unroll
            for (int j = 0; j < 4; ++j) {
                const int row = brow + wm * 128 + m * 16 + rg * 4 + j;
                out[(size_t)row * 2048 + col] =
                    (float)acc[m][n][j] * xs[row] * wsc + bv;
            }
        }
    }
#undef ST_A
#undef FRAG_A
#undef MFMA16
#undef BAR
#undef LGKM0
}

// ---------------------------------------------------------------------------
extern "C" void kernel_launch(void* const* d_in, const int* in_sizes, int n_in,
                              void* d_out, int out_size, void* d_ws, size_t ws_size,
                              hipStream_t stream) {
    const float* x    = (const float*)d_in[0];   // [B,N,D] = [4,4096,2048]
    const float* w    = (const float*)d_in[1];   // [O,D]   = [2048,2048]
    const float* bias = (const float*)d_in[2];   // [O]
    float* out = (float*)d_out;

    const int D = 2048;
    const int O = in_sizes[2];                   // 2048
    const int M = in_sizes[0] / D;               // 16384

    char* wsb = (char*)d_ws;
    signed char* xq  = (signed char*)wsb;
    signed char* wqt = (signed char*)(wsb + (size_t)M * D);
    float* xs  = (float*)(wsb + (size_t)M * D + (size_t)O * D);
    float* wsc = (float*)(wsb + (size_t)M * D + (size_t)O * D + (size_t)M * 4);

    quant_rows_2048<<<M / 4, 256, 0, stream>>>(x, xq, xs, 1e-12f);
    quant_w_t<<<O / 4, 256, 0, stream>>>(w, wqt, wsc);

    dim3 grid(O / 256, M / 256);   // (8, 64) = 512 blocks, %8 == 0
    gemm_i8_m201<<<grid, 512, 0, stream>>>(xq, wqt, xs, wsc, bias, out, D);
}